// Round 4
// baseline (56.837 us; speedup 1.0000x reference)
//
#include <hip/hip_runtime.h>
#include <hip/hip_bf16.h>

// Problem constants
#define BB 64
#define CC 512
#define DD 256
// loss = mean_{b,c} [ log(sum_k exp(2*S_bck)) - 2*S_bcc ],  S = Vn . Tn^T (rows L2-normalized)

typedef __attribute__((ext_vector_type(8))) short bf16x8;  // 8 bf16 = 4 VGPRs
typedef __attribute__((ext_vector_type(4))) float f32x4;

#define SW(row) (((row) & 7) << 4)

__device__ inline short f2bf(float f) {
    union { __hip_bfloat16 h; short s; } cv;
    cv.h = __float2bfloat16(f);
    return cv.s;
}

// Normalize a 256-elem row held by 8 threads (32 elems each in x[8]) and write bf16
// into LDS row `row` of dst_base with the 16B XOR swizzle.
__device__ inline void reduce_write(char* dst_base, int row, int ecolB, const float4* x) {
    float ss = 0.f;
#pragma unroll
    for (int q = 0; q < 8; ++q)
        ss += x[q].x * x[q].x + x[q].y * x[q].y + x[q].z * x[q].z + x[q].w * x[q].w;
    ss += __shfl_xor(ss, 1);
    ss += __shfl_xor(ss, 2);
    ss += __shfl_xor(ss, 4);  // 8 lanes own the row
    const float rinv = 1.0f / fmaxf(sqrtf(ss), 1e-12f);
    char* dstrow = dst_base + row * 512;
    const int sw = SW(row);
#pragma unroll
    for (int q2 = 0; q2 < 4; ++q2) {
        const float4 v0 = x[2 * q2], v1 = x[2 * q2 + 1];
        bf16x8 o;
        o[0] = f2bf(v0.x * rinv); o[1] = f2bf(v0.y * rinv);
        o[2] = f2bf(v0.z * rinv); o[3] = f2bf(v0.w * rinv);
        o[4] = f2bf(v1.x * rinv); o[5] = f2bf(v1.y * rinv);
        o[6] = f2bf(v1.z * rinv); o[7] = f2bf(v1.w * rinv);
        *reinterpret_cast<bf16x8*>(dstrow + ((ecolB + q2 * 16) ^ sw)) = o;
    }
}

// ---------------- Fused normalize + batched GEMM + loss ----------------
// 512 blocks = 64 batches x 8 row-blocks of 64 V-rows. 256 threads (4 waves), 64 KiB LDS
// -> 2 blocks/CU, 2 waves/SIMD. A (64x256) normalized into LDS then cached in regs
// (a[4][8]); its LDS region is re-used as the odd B buffer. B streamed in 64-row tiles,
// double-buffered, normalized on the fly from register-staged fp32 halves.
__global__ __launch_bounds__(256, 2) void gemm_loss(const float* __restrict__ V,
                                                    const float* __restrict__ T,
                                                    float* __restrict__ partials) {
    extern __shared__ char lds[];
    char* BufA = lds;          // 32 KiB: A tile, later odd-ct B buffer
    char* BufB = lds + 32768;  // 32 KiB: even-ct B buffer, later reduce scratch

    // XCD-aware remap: the 8 row-blocks of one batch land on one XCD (T panel L2 reuse)
    const int i0 = blockIdx.x;
    const int b  = (i0 & 7) * 8 + ((i0 >> 3) & 7);
    const int rb = i0 >> 6;

    const int tid  = threadIdx.x;
    const int lane = tid & 63;
    const int wave = tid >> 6;   // = wc: each wave owns 16 of each 64-col tile
    const int g    = lane >> 4;  // k-group 0..3
    const int ln   = lane & 15;
    const int rrow = tid >> 3;         // staging: 8 threads/row, 32 rows/pass
    const int ecolB = (tid & 7) * 64;  // byte offset of this thread's 32 bf16 elems

    const float* gV = V + (size_t)b * (CC * DD) + (size_t)rb * 64 * DD;
    const float* gT = T + (size_t)b * (CC * DD);

    // ---------- Prologue: issue ALL A + B0 loads, then normalize+write ----------
    {
        float4 xs[4][8];  // 128 VGPR transient (a[] not yet live)
#pragma unroll
        for (int p = 0; p < 2; ++p) {  // A rows p*32+rrow
            const float4* src =
                reinterpret_cast<const float4*>(gV + (size_t)(p * 32 + rrow) * DD + (tid & 7) * 32);
#pragma unroll
            for (int q = 0; q < 8; ++q) xs[p][q] = src[q];
        }
#pragma unroll
        for (int p = 0; p < 2; ++p) {  // B tile 0 rows p*32+rrow
            const float4* src =
                reinterpret_cast<const float4*>(gT + (size_t)(p * 32 + rrow) * DD + (tid & 7) * 32);
#pragma unroll
            for (int q = 0; q < 8; ++q) xs[2 + p][q] = src[q];
        }
#pragma unroll
        for (int p = 0; p < 2; ++p) reduce_write(BufA, p * 32 + rrow, ecolB, xs[p]);
#pragma unroll
        for (int p = 0; p < 2; ++p) reduce_write(BufB, p * 32 + rrow, ecolB, xs[2 + p]);
    }
    __syncthreads();

    // ---------- Cache A fragments in registers ----------
    bf16x8 a[4][8];
#pragma unroll
    for (int i = 0; i < 4; ++i) {
        const int row  = i * 16 + ln;
        const char* rp = BufA + row * 512;
        const int sw   = SW(row);
#pragma unroll
        for (int kk = 0; kk < 8; ++kk)
            a[i][kk] = *reinterpret_cast<const bf16x8*>(rp + ((kk * 64 + g * 16) ^ sw));
    }
    __syncthreads();  // protect BufA until all waves cached A (ct=0 writes tile1 there)

    float rs[4][4];  // rowsum of exp(2S) over this wave's 16-col slices
    float dg[4][4];  // diagonal 2*S term
#pragma unroll
    for (int i = 0; i < 4; ++i)
#pragma unroll
        for (int r = 0; r < 4; ++r) { rs[i][r] = 0.f; dg[i][r] = 0.f; }

    float4 x[8];  // 32-row half-tile staging (32 VGPR)

    for (int ct = 0; ct < 8; ++ct) {
        // ---- issue loads: next tile, half 1 (rows 0..31) ----
        if (ct < 7) {
            const float4* src = reinterpret_cast<const float4*>(
                gT + (size_t)((ct + 1) * 64 + rrow) * DD + (tid & 7) * 32);
#pragma unroll
            for (int q = 0; q < 8; ++q) x[q] = src[q];
        }

        // ---- MFMA on current tile ----
        const char* Bc = (ct & 1) ? BufA : BufB;
        f32x4 acc[4];
#pragma unroll
        for (int i = 0; i < 4; ++i) acc[i] = (f32x4){0.f, 0.f, 0.f, 0.f};
        {
            const int row  = wave * 16 + ln;
            const char* rp = Bc + row * 512;
            const int sw   = SW(row);
#pragma unroll
            for (int kk = 0; kk < 8; ++kk) {
                const bf16x8 bb =
                    *reinterpret_cast<const bf16x8*>(rp + ((kk * 64 + g * 16) ^ sw));
#pragma unroll
                for (int i = 0; i < 4; ++i)
                    acc[i] = __builtin_amdgcn_mfma_f32_16x16x32_bf16(a[i][kk], bb, acc[i], 0, 0, 0);
            }
        }

        char* Bn = (ct & 1) ? BufB : BufA;
        if (ct < 7) {
            // write half 1, then issue loads for half 2 (latency hides under epilogue)
            reduce_write(Bn, rrow, ecolB, x);
            const float4* src = reinterpret_cast<const float4*>(
                gT + (size_t)((ct + 1) * 64 + 32 + rrow) * DD + (tid & 7) * 32);
#pragma unroll
            for (int q = 0; q < 8; ++q) x[q] = src[q];
        }

        // ---- fused epilogue: exp(2*S) partial rowsum + diagonal grab ----
        const int gcol = ct * 64 + wave * 16 + ln;  // global col of this lane's acc slice
#pragma unroll
        for (int i = 0; i < 4; ++i) {
            const int grow = rb * 64 + i * 16 + g * 4;  // global row (+r)
#pragma unroll
            for (int r = 0; r < 4; ++r) {
                const float s2 = acc[i][r] * 2.0f;  // sim / TEMPERATURE
                rs[i][r] += __expf(s2);
                if (gcol == grow + r) dg[i][r] += s2;
            }
        }

        if (ct < 7) reduce_write(Bn, 32 + rrow, ecolB, x);  // write half 2
        __syncthreads();
    }

    // ---- per-row completion: combine the 4 waves' exp-sums BEFORE log ----
    float* vred = reinterpret_cast<float*>(BufB);  // [64][4]
    float* dred = vred + 256;                      // [64][4]
#pragma unroll
    for (int i = 0; i < 4; ++i)
#pragma unroll
        for (int r = 0; r < 4; ++r) {
            float v = rs[i][r];
            float d = dg[i][r];
#pragma unroll
            for (int m = 1; m < 16; m <<= 1) {  // reduce the 16 column-lanes
                v += __shfl_xor(v, m);
                d += __shfl_xor(d, m);
            }
            if (ln == 0) {
                const int rl = i * 16 + g * 4 + r;  // local row 0..63
                vred[rl * 4 + wave] = v;
                dred[rl * 4 + wave] = d;
            }
        }
    __syncthreads();

    if (wave == 0) {
        const float vv = vred[lane * 4] + vred[lane * 4 + 1] + vred[lane * 4 + 2] + vred[lane * 4 + 3];
        const float dd = dred[lane * 4] + dred[lane * 4 + 1] + dred[lane * 4 + 2] + dred[lane * 4 + 3];
        float lsum = logf(vv) - dd;
#pragma unroll
        for (int m = 1; m < 64; m <<= 1) lsum += __shfl_xor(lsum, m);
        if (lane == 0) partials[i0] = lsum;
    }
}

// ---------------- Final deterministic reduce (512 partials) ----------------
__global__ __launch_bounds__(256) void final_reduce(const float* __restrict__ partials,
                                                    float* __restrict__ out) {
    const int t = threadIdx.x;
    float v = partials[t] + partials[t + 256];
#pragma unroll
    for (int m = 1; m < 64; m <<= 1) v += __shfl_xor(v, m);
    __shared__ float red[4];
    if ((t & 63) == 0) red[t >> 6] = v;
    __syncthreads();
    if (t == 0) out[0] = (red[0] + red[1] + red[2] + red[3]) * (1.0f / 32768.0f);
}

extern "C" void kernel_launch(void* const* d_in, const int* in_sizes, int n_in,
                              void* d_out, int out_size, void* d_ws, size_t ws_size,
                              hipStream_t stream) {
    const float* vis = (const float*)d_in[0];
    const float* txt = (const float*)d_in[1];

    float* partials = (float*)d_ws;  // 512 floats
    float* out      = (float*)d_out;

    hipFuncSetAttribute((const void*)gemm_loss, hipFuncAttributeMaxDynamicSharedMemorySize,
                        65536);

    gemm_loss<<<512, 256, 65536, stream>>>(vis, txt, partials);
    final_reduce<<<1, 256, 0, stream>>>(partials, out);
}

// Round 5
// 39.120 us; speedup vs baseline: 1.4529x; 1.4529x over previous
//
#include <hip/hip_runtime.h>
#include <hip/hip_bf16.h>

// Problem constants
#define BB 64
#define CC 512
#define DD 256
// loss = mean_{b,c} [ log(sum_k exp(2*S_bck)) - 2*S_bcc ],  S = Vn . Tn^T (rows L2-normalized)

typedef __attribute__((ext_vector_type(8))) short bf16x8;  // 8 bf16 = 4 VGPRs
typedef __attribute__((ext_vector_type(4))) float f32x4;
typedef unsigned int u32;

#define SWZ(r) (((r) & 7) << 4)

__device__ inline short f2bf(float f) {
    union { __hip_bfloat16 h; short s; } cv;
    cv.h = __float2bfloat16(f);
    return cv.s;
}

// ---------------- Pass 1: L2-normalize T rows (fp32 in -> bf16 out), ~85% HBM ----------------
__global__ __launch_bounds__(256) void norm_rows(const float* __restrict__ in,
                                                 unsigned short* __restrict__ out) {
    const int row  = blockIdx.x * 4 + (threadIdx.x >> 6);
    const int lane = threadIdx.x & 63;
    const float4 x = reinterpret_cast<const float4*>(in)[(size_t)row * 64 + lane];
    float ss = x.x * x.x + x.y * x.y + x.z * x.z + x.w * x.w;
#pragma unroll
    for (int off = 32; off; off >>= 1) ss += __shfl_xor(ss, off);
    const float r = 1.0f / fmaxf(sqrtf(ss), 1e-12f);
    ushort4 o;
    o.x = (unsigned short)f2bf(x.x * r);
    o.y = (unsigned short)f2bf(x.y * r);
    o.z = (unsigned short)f2bf(x.z * r);
    o.w = (unsigned short)f2bf(x.w * r);
    reinterpret_cast<ushort4*>(out)[(size_t)row * 64 + lane] = o;
}

// ---------------- Pass 2: fused V-norm + batched GEMM + loss ----------------
// 512 blocks = 64 batches x 8 row-blocks of 64 V-rows; 4 waves; 64 KiB static LDS
// (2 blocks/CU). B (pre-normalized bf16 T rows) staged by global_load_lds width=16 with
// PRE-SWIZZLED global source (LDS dest stays linear; content lands XOR-swizzled).
// A (64 fp32 V rows) normalized in the prologue, routed via LDS buf1, cached in regs.
// One barrier per 64-row B tile; DMA prefetch is drained by the barrier's vmcnt(0).
__global__ __launch_bounds__(256, 2) void gemm_loss(const float* __restrict__ V,
                                                    const unsigned short* __restrict__ Tn,
                                                    float* __restrict__ partials) {
    __shared__ char lds[65536];  // buf0 = lds, buf1 = lds+32768 (tile ct lives in buf[ct&1])

    // XCD-aware remap: the 8 row-blocks of one batch land on one XCD (T panel L2 reuse)
    const int i0 = blockIdx.x;
    const int b  = (i0 & 7) * 8 + ((i0 >> 3) & 7);
    const int rb = i0 >> 6;

    const int tid  = threadIdx.x;
    const int lane = tid & 63;
    const int wave = tid >> 6;   // each wave owns 16 cols of every 64-col tile
    const int g    = lane >> 4;  // k-group 0..3
    const int ln   = lane & 15;

    const float* gV = V + (size_t)b * (CC * DD) + (size_t)rb * 64 * DD;
    const char*  gT = reinterpret_cast<const char*>(Tn + (size_t)b * (CC * DD));  // 512 B rows

    // ---- issue async DMA: B tile 0 -> buf0 (overlaps the whole A prologue) ----
#pragma unroll
    for (int r2 = 0; r2 < 8; ++r2) {
        const int L   = wave * 8192 + r2 * 1024 + (lane << 4);  // linear LDS byte (incl. lane*16)
        const int row = L >> 9, inrow = L & 511;
        __builtin_amdgcn_global_load_lds((const u32*)(gT + row * 512 + (inrow ^ SWZ(row))),
                                         (u32*)(lds + wave * 8192 + r2 * 1024), 16, 0, 0);
    }

    // ---- A prologue: load 64 fp32 rows, L2-normalize, write bf16 swizzled into buf1 ----
    {
        const int rrow  = tid >> 3;        // 8 threads/row, 32 rows/pass
        const int ecolB = (tid & 7) * 64;  // byte offset of this thread's 32 bf16 elems
        char* bufA = lds + 32768;
#pragma unroll
        for (int p = 0; p < 2; ++p) {
            const float4* src =
                reinterpret_cast<const float4*>(gV + (size_t)(p * 32 + rrow) * DD) + (tid & 7) * 8;
            float4 x[8];
#pragma unroll
            for (int q = 0; q < 8; ++q) x[q] = src[q];
            float ss = 0.f;
#pragma unroll
            for (int q = 0; q < 8; ++q)
                ss += x[q].x * x[q].x + x[q].y * x[q].y + x[q].z * x[q].z + x[q].w * x[q].w;
            ss += __shfl_xor(ss, 1);
            ss += __shfl_xor(ss, 2);
            ss += __shfl_xor(ss, 4);  // 8 lanes own the row
            const float rinv = 1.0f / fmaxf(sqrtf(ss), 1e-12f);
            const int row = p * 32 + rrow;
            char* dstrow  = bufA + row * 512;
            const int sw  = SWZ(row);
#pragma unroll
            for (int q2 = 0; q2 < 4; ++q2) {
                const float4 v0 = x[2 * q2], v1 = x[2 * q2 + 1];
                bf16x8 o;
                o[0] = f2bf(v0.x * rinv); o[1] = f2bf(v0.y * rinv);
                o[2] = f2bf(v0.z * rinv); o[3] = f2bf(v0.w * rinv);
                o[4] = f2bf(v1.x * rinv); o[5] = f2bf(v1.y * rinv);
                o[6] = f2bf(v1.z * rinv); o[7] = f2bf(v1.w * rinv);
                *reinterpret_cast<bf16x8*>(dstrow + ((ecolB + q2 * 16) ^ sw)) = o;
            }
        }
    }
    __syncthreads();

    // ---- cache A fragments in registers (a[4][8] = 128 VGPR) ----
    bf16x8 a[4][8];
#pragma unroll
    for (int i = 0; i < 4; ++i) {
        const int row  = i * 16 + ln;
        const char* rp = lds + 32768 + row * 512;
        const int sw   = SWZ(row);
#pragma unroll
        for (int kk = 0; kk < 8; ++kk)
            a[i][kk] = *reinterpret_cast<const bf16x8*>(rp + ((kk * 64 + g * 16) ^ sw));
    }
    __syncthreads();  // all a[] reads done (buf1 reusable); drains vmcnt -> B0 landed

    float rs[4][4];  // rowsum of exp(2S) over this wave's 16-col slices
    float dg[4][4];  // diagonal 2*S term
#pragma unroll
    for (int i = 0; i < 4; ++i)
#pragma unroll
        for (int r = 0; r < 4; ++r) { rs[i][r] = 0.f; dg[i][r] = 0.f; }

    for (int ct = 0; ct < 8; ++ct) {
        // ---- issue DMA for tile ct+1 into the other buffer (consumed tile ct-1) ----
        if (ct < 7) {
            const char* gtile = gT + (size_t)(ct + 1) * 64 * 512;
            char* dst = lds + ((ct & 1) ? 0 : 32768);  // buf[(ct+1)&1]
#pragma unroll
            for (int r2 = 0; r2 < 8; ++r2) {
                const int L   = wave * 8192 + r2 * 1024 + (lane << 4);
                const int row = L >> 9, inrow = L & 511;
                __builtin_amdgcn_global_load_lds(
                    (const u32*)(gtile + row * 512 + (inrow ^ SWZ(row))),
                    (u32*)(dst + wave * 8192 + r2 * 1024), 16, 0, 0);
            }
        }

        // ---- MFMA on current tile (1 ds_read : 4 MFMA per kk) ----
        const char* Bc = lds + ((ct & 1) ? 32768 : 0);
        f32x4 acc[4];
#pragma unroll
        for (int i = 0; i < 4; ++i) acc[i] = (f32x4){0.f, 0.f, 0.f, 0.f};
        {
            const int row  = wave * 16 + ln;
            const char* rp = Bc + row * 512;
            const int sw   = SWZ(row);
#pragma unroll
            for (int kk = 0; kk < 8; ++kk) {
                const bf16x8 bb = *reinterpret_cast<const bf16x8*>(rp + ((kk * 64 + g * 16) ^ sw));
#pragma unroll
                for (int i = 0; i < 4; ++i)
                    acc[i] = __builtin_amdgcn_mfma_f32_16x16x32_bf16(a[i][kk], bb, acc[i], 0, 0, 0);
            }
        }

        // ---- fused epilogue: exp(2*S) partial rowsum + diagonal grab ----
        const int gcol = ct * 64 + wave * 16 + ln;  // global col of this lane's acc slice
#pragma unroll
        for (int i = 0; i < 4; ++i) {
            const int grow = rb * 64 + i * 16 + g * 4;  // global row (+r)
#pragma unroll
            for (int r = 0; r < 4; ++r) {
                const float s2 = acc[i][r] * 2.0f;  // sim / TEMPERATURE
                rs[i][r] += __expf(s2);
                if (gcol == grow + r) dg[i][r] += s2;
            }
        }
        __syncthreads();  // tile ct consumed; DMA for ct+1 drained (vmcnt 0)
    }

    // ---- per-row completion: combine the 4 waves' exp-sums BEFORE log ----
    float* vred = reinterpret_cast<float*>(lds);  // [64][4]
    float* dred = vred + 256;                     // [64][4]
#pragma unroll
    for (int i = 0; i < 4; ++i)
#pragma unroll
        for (int r = 0; r < 4; ++r) {
            float v = rs[i][r];
            float d = dg[i][r];
#pragma unroll
            for (int m = 1; m < 16; m <<= 1) {  // reduce the 16 column-lanes
                v += __shfl_xor(v, m);
                d += __shfl_xor(d, m);
            }
            if (ln == 0) {
                const int rl = i * 16 + g * 4 + r;  // local row 0..63
                vred[rl * 4 + wave] = v;
                dred[rl * 4 + wave] = d;
            }
        }
    __syncthreads();

    if (wave == 0) {
        const float vv =
            vred[lane * 4] + vred[lane * 4 + 1] + vred[lane * 4 + 2] + vred[lane * 4 + 3];
        const float dd =
            dred[lane * 4] + dred[lane * 4 + 1] + dred[lane * 4 + 2] + dred[lane * 4 + 3];
        float lsum = logf(vv) - dd;
#pragma unroll
        for (int m = 1; m < 64; m <<= 1) lsum += __shfl_xor(lsum, m);
        if (lane == 0) partials[i0] = lsum;
    }
}

// ---------------- Final deterministic reduce (512 partials) ----------------
__global__ __launch_bounds__(256) void final_reduce(const float* __restrict__ partials,
                                                    float* __restrict__ out) {
    const int t = threadIdx.x;
    float v = partials[t] + partials[t + 256];
#pragma unroll
    for (int m = 1; m < 64; m <<= 1) v += __shfl_xor(v, m);
    __shared__ float red[4];
    if ((t & 63) == 0) red[t >> 6] = v;
    __syncthreads();
    if (t == 0) out[0] = (red[0] + red[1] + red[2] + red[3]) * (1.0f / 32768.0f);
}

extern "C" void kernel_launch(void* const* d_in, const int* in_sizes, int n_in,
                              void* d_out, int out_size, void* d_ws, size_t ws_size,
                              hipStream_t stream) {
    const float* vis = (const float*)d_in[0];
    const float* txt = (const float*)d_in[1];

    unsigned short* Tn = (unsigned short*)d_ws;                       // 64*512*256 bf16 = 16.8 MB
    float* partials    = (float*)((char*)d_ws + (size_t)BB * CC * DD * 2);  // 512 floats
    float* out         = (float*)d_out;

    norm_rows<<<8192, 256, 0, stream>>>(txt, Tn);
    gemm_loss<<<512, 256, 0, stream>>>(vis, Tn, partials);
    final_reduce<<<1, 256, 0, stream>>>(partials, out);
}